// Round 2
// baseline (559.371 us; speedup 1.0000x reference)
//
#include <hip/hip_runtime.h>
#include <math.h>

#define D 128
#define LLEN 200
#define SLEN 50
#define NEGINF (-1e9f)

__device__ __forceinline__ float wave_red_max(float v) {
#pragma unroll
  for (int m = 32; m >= 1; m >>= 1) v = fmaxf(v, __shfl_xor(v, m, 64));
  return v;
}
__device__ __forceinline__ float wave_red_sum(float v) {
#pragma unroll
  for (int m = 32; m >= 1; m >>= 1) v += __shfl_xor(v, m, 64);
  return v;
}

// 256-thread block reductions; red is 4-float LDS scratch. ALL threads must call.
__device__ __forceinline__ float block_max(float v, float* red) {
  v = wave_red_max(v);
  if ((threadIdx.x & 63) == 0) red[threadIdx.x >> 6] = v;
  __syncthreads();
  v = fmaxf(fmaxf(red[0], red[1]), fmaxf(red[2], red[3]));
  __syncthreads();
  return v;
}
__device__ __forceinline__ float block_sum(float v, float* red) {
  v = wave_red_sum(v);
  if ((threadIdx.x & 63) == 0) red[threadIdx.x >> 6] = v;
  __syncthreads();
  v = red[0] + red[1] + red[2] + red[3];
  __syncthreads();
  return v;
}

// logit for one item: relu( u_part + e @ W1[128:256,:] ) @ W2 + b2
// Software-pipelined: 8 chunks of 16 floats, double-buffered (4 float4 loads
// in flight while FMA-ing the previous chunk). sched_barrier(0) keeps the
// compiler from sinking the loads back next to their uses (VGPR=40 pathology).
__device__ __forceinline__ float item_logit(const float* ep,
                                            const float* __restrict__ W1,
                                            const float* __restrict__ W2,
                                            const float* upart, float b2v) {
  float acc[16];
#pragma unroll
  for (int j = 0; j < 16; ++j) acc[j] = 0.f;

  const float4* ep4 = reinterpret_cast<const float4*>(ep);
  float4 buf0[4], buf1[4];
#pragma unroll
  for (int t = 0; t < 4; ++t) buf0[t] = ep4[t];

#pragma unroll
  for (int c = 0; c < 8; ++c) {
    float4* cur = (c & 1) ? buf1 : buf0;
    float4* nxt = (c & 1) ? buf0 : buf1;
    if (c < 7) {
#pragma unroll
      for (int t = 0; t < 4; ++t) nxt[t] = ep4[(c + 1) * 4 + t];
    }
    __builtin_amdgcn_sched_barrier(0);
    const float* wb = W1 + (size_t)(D + c * 16) * 16;  // lane-uniform -> s_load
#pragma unroll
    for (int t = 0; t < 4; ++t) {
      float e0 = cur[t].x, e1 = cur[t].y, e2 = cur[t].z, e3 = cur[t].w;
#pragma unroll
      for (int j = 0; j < 16; ++j) {
        float a = acc[j];
        a = fmaf(e0, wb[(4 * t + 0) * 16 + j], a);
        a = fmaf(e1, wb[(4 * t + 1) * 16 + j], a);
        a = fmaf(e2, wb[(4 * t + 2) * 16 + j], a);
        a = fmaf(e3, wb[(4 * t + 3) * 16 + j], a);
        acc[j] = a;
      }
    }
  }
  float hs = 0.f;
#pragma unroll
  for (int j = 0; j < 16; ++j)
    hs = fmaf(fmaxf(upart[j] + acc[j], 0.f), W2[j], hs);
  return hs + b2v;
}

__global__ void __launch_bounds__(256) din_kernel(
    const float* __restrict__ user_table, const float* __restrict__ item_table,
    const float* __restrict__ W1, const float* __restrict__ b1,
    const float* __restrict__ W2, const float* __restrict__ b2,
    const int* __restrict__ user_inputs, const int* __restrict__ L_inputs,
    const int* __restrict__ S_inputs, const int* __restrict__ item_inputs,
    float* __restrict__ out) {
  __shared__ float u_sh[D];
  __shared__ float upart_sh[16];
  __shared__ float w_sh[256];      // logits -> unnormalized weights
  __shared__ int rows_sh[256];     // gathered (clamped) row ids
  __shared__ __align__(16) float ulong_sh[D];
  __shared__ float uh_sh[D];
  __shared__ float part_sh[256];
  __shared__ float red_sh[4];

  const int b = blockIdx.x;
  const int tid = threadIdx.x;

  // ---- user embedding ----
  const int uid = user_inputs[b];
  if (tid < D) u_sh[tid] = user_table[(size_t)uid * D + tid];
  __syncthreads();

  // ---- u_part[j] = b1[j] + u @ W1[0:128,:] ----
  {
    int j = tid & 15, g = tid >> 4;  // 16 groups x 16 j
    float p = 0.f;
#pragma unroll
    for (int dd = 0; dd < 8; ++dd) {
      int d = g * 8 + dd;
      p = fmaf(u_sh[d], W1[d * 16 + j], p);
    }
    part_sh[tid] = p;  // tid == g*16 + j
  }
  __syncthreads();
  if (tid < 16) {
    float s = b1[tid];
#pragma unroll
    for (int g = 0; g < 16; ++g) s += part_sh[g * 16 + tid];
    upart_sh[tid] = s;
  }
  __syncthreads();

  const float b2v = b2[0];

  // ---- stage 1: logits over L history (item-per-thread) ----
  float logit = NEGINF;
  if (tid < LLEN) {
    int idx = L_inputs[(size_t)b * LLEN + tid];
    int row = (idx >= 0) ? idx : 0;
    rows_sh[tid] = row;
    float lg = item_logit(item_table + (size_t)row * D, W1, W2, upart_sh, b2v);
    logit = (idx >= 0) ? lg : NEGINF;
  }
  float m1 = block_max(logit, red_sh);
  float p1 = (tid < LLEN) ? expf(logit - m1) : 0.f;
  if (tid < LLEN) w_sh[tid] = p1;
  float S1 = block_sum(p1, red_sh);  // barrier inside also publishes w_sh
  float invS1 = 1.f / S1;

  // ---- u_long[d] = (1/S1) * sum_l p_l * e_l[d]  (10 loads in flight) ----
  {
    int d = tid & (D - 1), h = tid >> 7;
    int base = h * 100;
    float acc = 0.f;
#pragma unroll
    for (int c = 0; c < 10; ++c) {
      float v[10];
#pragma unroll
      for (int k = 0; k < 10; ++k)
        v[k] = item_table[(size_t)rows_sh[base + c * 10 + k] * D + d];
#pragma unroll
      for (int k = 0; k < 10; ++k)
        acc = fmaf(w_sh[base + c * 10 + k], v[k], acc);
    }
    part_sh[tid] = acc;  // tid == h*128 + d
  }
  __syncthreads();
  if (tid < D) ulong_sh[tid] = (part_sh[tid] + part_sh[tid + D]) * invS1;
  __syncthreads();

  // ---- stage 2: logits over [u_long] + S (13 items per wave) ----
  {
    int lane = tid & 63, wv = tid >> 6;
    int sitem = wv * 13 + lane;
    if (lane < 13 && sitem < SLEN + 1) {
      const float* ep;
      bool valid = true;
      int srow = 0;
      if (sitem == 0) {
        ep = ulong_sh;
      } else {
        int idx = S_inputs[(size_t)b * SLEN + (sitem - 1)];
        valid = (idx >= 0);
        srow = valid ? idx : 0;
        ep = item_table + (size_t)srow * D;
      }
      float lg = item_logit(ep, W1, W2, upart_sh, b2v);
      w_sh[sitem] = valid ? lg : NEGINF;
      rows_sh[sitem] = srow;
    }
  }
  __syncthreads();

  const int n2 = SLEN + 1;
  float lg2 = (tid < n2) ? w_sh[tid] : NEGINF;
  float m2 = block_max(lg2, red_sh);
  float p2 = (tid < n2) ? expf(lg2 - m2) : 0.f;
  float S2 = block_sum(p2, red_sh);
  if (tid < n2) w_sh[tid] = p2;
  __syncthreads();
  float invS2 = 1.f / S2;

  // ---- user_hybrid[d]  (5 loads in flight, s=0 handled in half 0) ----
  {
    int d = tid & (D - 1), h = tid >> 7;
    float acc = (h == 0) ? w_sh[0] * ulong_sh[d] : 0.f;
    int sbase = 1 + h * 25;
#pragma unroll
    for (int c = 0; c < 5; ++c) {
      float v[5];
#pragma unroll
      for (int k = 0; k < 5; ++k)
        v[k] = item_table[(size_t)rows_sh[sbase + c * 5 + k] * D + d];
#pragma unroll
      for (int k = 0; k < 5; ++k)
        acc = fmaf(w_sh[sbase + c * 5 + k], v[k], acc);
    }
    part_sh[tid] = acc;
  }
  __syncthreads();
  if (tid < D) uh_sh[tid] = (part_sh[tid] + part_sh[tid + D]) * invS2;
  __syncthreads();

  // ---- score = dot(user_hybrid, item_emb) ----
  float sv = 0.f;
  if (tid < D) {
    int irow = item_inputs[b];
    sv = uh_sh[tid] * item_table[(size_t)irow * D + tid];
  }
  float tot = block_sum(sv, red_sh);
  if (tid == 0) out[b] = tot;
}

extern "C" void kernel_launch(void* const* d_in, const int* in_sizes, int n_in,
                              void* d_out, int out_size, void* d_ws, size_t ws_size,
                              hipStream_t stream) {
  const float* user_table = (const float*)d_in[0];
  const float* item_table = (const float*)d_in[1];
  const float* W1 = (const float*)d_in[2];
  const float* b1 = (const float*)d_in[3];
  const float* W2 = (const float*)d_in[4];
  const float* b2 = (const float*)d_in[5];
  const int* user_inputs = (const int*)d_in[6];
  const int* L_inputs = (const int*)d_in[7];
  const int* S_inputs = (const int*)d_in[8];
  const int* item_inputs = (const int*)d_in[9];
  float* out = (float*)d_out;

  const int B = in_sizes[6];  // 4096
  din_kernel<<<B, 256, 0, stream>>>(user_table, item_table, W1, b1, W2, b2,
                                    user_inputs, L_inputs, S_inputs, item_inputs,
                                    out);
}

// Round 3
// 449.126 us; speedup vs baseline: 1.2455x; 1.2455x over previous
//
#include <hip/hip_runtime.h>
#include <math.h>

#define D 128
#define LLEN 200
#define SLEN 50
#define CH 64            // stage-1 chunk rows (64,64,64,8)
#define ROWP 33          // padded row stride in float4 (bank spread)
#define NEG (-1e9f)

__device__ __forceinline__ float wave_red_max(float v) {
#pragma unroll
  for (int m = 32; m >= 1; m >>= 1) v = fmaxf(v, __shfl_xor(v, m, 64));
  return v;
}
__device__ __forceinline__ float wave_red_sum(float v) {
#pragma unroll
  for (int m = 32; m >= 1; m >>= 1) v += __shfl_xor(v, m, 64);
  return v;
}
// 256-thread block reductions; ALL threads must call.
__device__ __forceinline__ float block_max(float v, float* red) {
  v = wave_red_max(v);
  if ((threadIdx.x & 63) == 0) red[threadIdx.x >> 6] = v;
  __syncthreads();
  v = fmaxf(fmaxf(red[0], red[1]), fmaxf(red[2], red[3]));
  __syncthreads();
  return v;
}
__device__ __forceinline__ float block_sum(float v, float* red) {
  v = wave_red_sum(v);
  if ((threadIdx.x & 63) == 0) red[threadIdx.x >> 6] = v;
  __syncthreads();
  v = red[0] + red[1] + red[2] + red[3];
  __syncthreads();
  return v;
}

// logit = relu(upart + e @ W1[128:256,:]) @ W2 + b2 ; e read from LDS (float4*)
__device__ __forceinline__ float item_logit_lds(const float4* e4,
                                                const float* __restrict__ W1,
                                                const float* __restrict__ W2,
                                                const float* upart, float b2v) {
  float acc[16];
#pragma unroll
  for (int j = 0; j < 16; ++j) acc[j] = 0.f;
#pragma unroll
  for (int t = 0; t < 32; ++t) {
    float4 v = e4[t];
    const float* wb = &W1[(size_t)(D + 4 * t) * 16];  // lane-uniform -> s_load
#pragma unroll
    for (int j = 0; j < 16; ++j) {
      float a = acc[j];
      a = fmaf(v.x, wb[0 * 16 + j], a);
      a = fmaf(v.y, wb[1 * 16 + j], a);
      a = fmaf(v.z, wb[2 * 16 + j], a);
      a = fmaf(v.w, wb[3 * 16 + j], a);
      acc[j] = a;
    }
  }
  float hs = 0.f;
#pragma unroll
  for (int j = 0; j < 16; ++j)
    hs = fmaf(fmaxf(upart[j] + acc[j], 0.f), W2[j], hs);
  return hs + b2v;
}

__device__ __forceinline__ float4 row_ld(const float4* it4, const int* rids,
                                         int base, int s) {
  int r = s >> 5;
  int gid = rids[base + r];
  gid = gid < 0 ? 0 : gid;
  return it4[(size_t)gid * 32 + (s & 31)];
}
__device__ __forceinline__ int eslot(int s) { return (s >> 5) * ROWP + (s & 31); }

__global__ void __launch_bounds__(256, 4) din_kernel(
    const float* __restrict__ user_table, const float* __restrict__ item_table,
    const float* __restrict__ W1, const float* __restrict__ b1,
    const float* __restrict__ W2, const float* __restrict__ b2,
    const int* __restrict__ user_inputs, const int* __restrict__ L_inputs,
    const int* __restrict__ S_inputs, const int* __restrict__ item_inputs,
    float* __restrict__ out) {
  __shared__ float4 ebuf4[CH * ROWP];  // staged rows (padded stride)
  __shared__ float4 part4[256];        // weighted-sum partials / upart scratch
  __shared__ float4 ulong4[32];        // u_long
  __shared__ float w_sh[CH];           // per-chunk softmax weights
  __shared__ int rows1[LLEN];          // raw L indices
  __shared__ int rowsS[SLEN];          // raw S indices
  __shared__ float u_sh[D];
  __shared__ float upart_sh[16];
  __shared__ float red_sh[4];

  const int b = blockIdx.x;
  const int tid = threadIdx.x;
  const float4* it4 = reinterpret_cast<const float4*>(item_table);

  // ---- phase 1: indices + user embedding ----
  if (tid < D) u_sh[tid] = user_table[(size_t)user_inputs[b] * D + tid];
  if (tid < LLEN) rows1[tid] = L_inputs[(size_t)b * LLEN + tid];
  if (tid < SLEN) rowsS[tid] = S_inputs[(size_t)b * SLEN + tid];
  __syncthreads();

  // ---- u_part[j] = b1[j] + u @ W1[0:128,:] ----
  {
    int j = tid & 15, g = tid >> 4;
    float p = 0.f;
#pragma unroll
    for (int dd = 0; dd < 8; ++dd) {
      int d = g * 8 + dd;
      p = fmaf(u_sh[d], W1[d * 16 + j], p);
    }
    reinterpret_cast<float*>(part4)[tid] = p;
  }
  __syncthreads();
  if (tid < 16) {
    float s = b1[tid];
#pragma unroll
    for (int g = 0; g < 16; ++g) s += reinterpret_cast<float*>(part4)[g * 16 + tid];
    upart_sh[tid] = s;
  }
  __syncthreads();

  const float b2v = b2[0];

  // ---- stage 1: chunked online-softmax attention over L ----
  float m_run = NEG, S_run = 0.f;
  float4 uacc = make_float4(0.f, 0.f, 0.f, 0.f);
  const int col = tid & 31, grp = tid >> 5;  // for weighted accumulate

  for (int c = 0; c < 4; ++c) {
    const int base = c * CH;
    const int cnt = (base + CH <= LLEN) ? CH : (LLEN - base);  // 64,64,64,8
    const int nslot = cnt * 32;

    // -- stage rows into LDS: coalesced, 4 independent loads in flight --
    for (int s0 = tid; s0 < nslot; s0 += 1024) {
      int s1 = s0 + 256, s2 = s0 + 512, s3 = s0 + 768;
      float4 v0, v1, v2, v3;
      v0 = row_ld(it4, rows1, base, s0);
      if (s1 < nslot) v1 = row_ld(it4, rows1, base, s1);
      if (s2 < nslot) v2 = row_ld(it4, rows1, base, s2);
      if (s3 < nslot) v3 = row_ld(it4, rows1, base, s3);
      ebuf4[eslot(s0)] = v0;
      if (s1 < nslot) ebuf4[eslot(s1)] = v1;
      if (s2 < nslot) ebuf4[eslot(s2)] = v2;
      if (s3 < nslot) ebuf4[eslot(s3)] = v3;
    }
    __syncthreads();

    // -- logits (item-per-thread, e from LDS, W1 via s_load) --
    float lg = NEG;
    if (tid < cnt) {
      float l = item_logit_lds(&ebuf4[tid * ROWP], W1, W2, upart_sh, b2v);
      lg = (rows1[base + tid] >= 0) ? l : NEG;
    }
    float mc = block_max(lg, red_sh);
    float m_new = fmaxf(m_run, mc);
    float alpha = expf(m_run - m_new);
    float p = (tid < cnt) ? expf(lg - m_new) : 0.f;
    if (tid < cnt) w_sh[tid] = p;
    float Sc = block_sum(p, red_sh);  // internal barrier publishes w_sh
    S_run = S_run * alpha + Sc;
    m_run = m_new;

    // -- weighted accumulate from LDS --
    uacc.x *= alpha; uacc.y *= alpha; uacc.z *= alpha; uacc.w *= alpha;
    for (int l = grp; l < cnt; l += 8) {
      float pw = w_sh[l];
      float4 e = ebuf4[l * ROWP + col];
      uacc.x = fmaf(pw, e.x, uacc.x);
      uacc.y = fmaf(pw, e.y, uacc.y);
      uacc.z = fmaf(pw, e.z, uacc.z);
      uacc.w = fmaf(pw, e.w, uacc.w);
    }
    __syncthreads();  // ebuf/w_sh reuse next chunk
  }

  // ---- reduce u_long ----
  part4[tid] = uacc;
  __syncthreads();
  if (tid < 32) {
    float4 t = part4[tid];
#pragma unroll
    for (int g = 1; g < 8; ++g) {
      float4 o = part4[g * 32 + tid];
      t.x += o.x; t.y += o.y; t.z += o.z; t.w += o.w;
    }
    float inv = 1.f / S_run;
    t.x *= inv; t.y *= inv; t.z *= inv; t.w *= inv;
    ulong4[tid] = t;
  }
  __syncthreads();

  // ---- stage 2: stage S rows, softmax over [u_long]+S ----
  {
    const int nslot = SLEN * 32;  // 1600
    for (int s0 = tid; s0 < nslot; s0 += 1024) {
      int s1 = s0 + 256, s2 = s0 + 512, s3 = s0 + 768;
      float4 v0, v1, v2, v3;
      v0 = row_ld(it4, rowsS, 0, s0);
      if (s1 < nslot) v1 = row_ld(it4, rowsS, 0, s1);
      if (s2 < nslot) v2 = row_ld(it4, rowsS, 0, s2);
      if (s3 < nslot) v3 = row_ld(it4, rowsS, 0, s3);
      ebuf4[eslot(s0)] = v0;
      if (s1 < nslot) ebuf4[eslot(s1)] = v1;
      if (s2 < nslot) ebuf4[eslot(s2)] = v2;
      if (s3 < nslot) ebuf4[eslot(s3)] = v3;
    }
    __syncthreads();
  }

  float lg2 = NEG;
  if (tid < 1 + SLEN) {
    const float4* ep = (tid == 0) ? ulong4 : &ebuf4[(tid - 1) * ROWP];
    float l = item_logit_lds(ep, W1, W2, upart_sh, b2v);
    bool valid = (tid == 0) || (rowsS[tid - 1] >= 0);
    lg2 = valid ? l : NEG;
  }
  float m2 = block_max(lg2, red_sh);
  float p2 = (tid < 1 + SLEN) ? expf(lg2 - m2) : 0.f;
  if (tid < 1 + SLEN) w_sh[tid] = p2;
  float S2 = block_sum(p2, red_sh);
  float invS2 = 1.f / S2;

  // ---- user_hybrid partials + final score ----
  float4 acc2 = make_float4(0.f, 0.f, 0.f, 0.f);
  for (int l = grp; l < 1 + SLEN; l += 8) {
    float pw = w_sh[l];
    float4 e = (l == 0) ? ulong4[col] : ebuf4[(l - 1) * ROWP + col];
    acc2.x = fmaf(pw, e.x, acc2.x);
    acc2.y = fmaf(pw, e.y, acc2.y);
    acc2.z = fmaf(pw, e.z, acc2.z);
    acc2.w = fmaf(pw, e.w, acc2.w);
  }
  part4[tid] = acc2;
  __syncthreads();
  float sv = 0.f;
  if (tid < 32) {
    float4 t = part4[tid];
#pragma unroll
    for (int g = 1; g < 8; ++g) {
      float4 o = part4[g * 32 + tid];
      t.x += o.x; t.y += o.y; t.z += o.z; t.w += o.w;
    }
    float4 iv = it4[(size_t)item_inputs[b] * 32 + tid];
    sv = (t.x * iv.x + t.y * iv.y + t.z * iv.z + t.w * iv.w) * invS2;
  }
  float tot = block_sum(sv, red_sh);
  if (tid == 0) out[b] = tot;
}

extern "C" void kernel_launch(void* const* d_in, const int* in_sizes, int n_in,
                              void* d_out, int out_size, void* d_ws, size_t ws_size,
                              hipStream_t stream) {
  const float* user_table = (const float*)d_in[0];
  const float* item_table = (const float*)d_in[1];
  const float* W1 = (const float*)d_in[2];
  const float* b1 = (const float*)d_in[3];
  const float* W2 = (const float*)d_in[4];
  const float* b2 = (const float*)d_in[5];
  const int* user_inputs = (const int*)d_in[6];
  const int* L_inputs = (const int*)d_in[7];
  const int* S_inputs = (const int*)d_in[8];
  const int* item_inputs = (const int*)d_in[9];
  float* out = (float*)d_out;

  const int B = in_sizes[6];  // 4096
  din_kernel<<<B, 256, 0, stream>>>(user_table, item_table, W1, b1, W2, b2,
                                    user_inputs, L_inputs, S_inputs, item_inputs,
                                    out);
}

// Round 4
// 297.812 us; speedup vs baseline: 1.8783x; 1.5081x over previous
//
#include <hip/hip_runtime.h>
#include <math.h>

#define D 128
#define LLEN 200
#define SLEN 50
#define CH 64
#define ESTR 129          // LDS row stride in floats: bank = (row + d) % 32 -> 2-way = free
#define NEG (-1e9f)

__device__ __forceinline__ float wave_red_sum(float v) {
#pragma unroll
  for (int m = 32; m >= 1; m >>= 1) v += __shfl_xor(v, m, 64);
  return v;
}
// 256-thread block sum; ALL threads must call.
__device__ __forceinline__ float block_sum(float v, float* red) {
  v = wave_red_sum(v);
  if ((threadIdx.x & 63) == 0) red[threadIdx.x >> 6] = v;
  __syncthreads();
  v = red[0] + red[1] + red[2] + red[3];
  __syncthreads();
  return v;
}

__global__ void __launch_bounds__(256, 4) din_kernel(
    const float* __restrict__ user_table, const float* __restrict__ item_table,
    const float* __restrict__ W1, const float* __restrict__ b1,
    const float* __restrict__ W2, const float* __restrict__ b2,
    const int* __restrict__ user_inputs, const int* __restrict__ L_inputs,
    const int* __restrict__ S_inputs, const int* __restrict__ item_inputs,
    float* __restrict__ out) {
  __shared__ float ebuf[CH * ESTR];   // 33,024B staged rows; also prolog/epilog scratch
  __shared__ float hspart[4 * 65];    // per-wave hs partials, stride 65 (conflict-free)
  __shared__ float w_sh[CH];          // unnormalized softmax weights for current chunk
  __shared__ int rows1[LLEN];
  __shared__ int rowsS[SLEN];
  __shared__ float upart_sh[16];
  __shared__ float red_sh[4];

  const int b = blockIdx.x;
  const int tid = threadIdx.x;
  const int lane = tid & 63;
  const int w = __builtin_amdgcn_readfirstlane(tid >> 6);  // wave id -> SGPR (W1 s_load)
  const int dd = tid & 127, dg = tid >> 7;                 // weighted-sum roles
  const float4* it4 = reinterpret_cast<const float4*>(item_table);

  // ---- prolog: indices + user embedding (u_sh/part alias into ebuf) ----
  float* u_sh = &ebuf[0];
  float* part = &ebuf[128];
  if (tid < D) u_sh[tid] = user_table[(size_t)user_inputs[b] * D + tid];
  if (tid < LLEN) rows1[tid] = L_inputs[(size_t)b * LLEN + tid];
  if (tid < SLEN) rowsS[tid] = S_inputs[(size_t)b * SLEN + tid];
  __syncthreads();

  // u_part[j] = b1[j] + u @ W1[0:128,:]
  {
    int j = tid & 15, g = tid >> 4;
    float p = 0.f;
#pragma unroll
    for (int t = 0; t < 8; ++t) {
      int d = g * 8 + t;
      p = fmaf(u_sh[d], W1[d * 16 + j], p);
    }
    part[tid] = p;
  }
  __syncthreads();
  if (tid < 16) {
    float s = b1[tid];
#pragma unroll
    for (int g = 0; g < 16; ++g) s += part[g * 16 + tid];
    upart_sh[tid] = s;
  }
  __syncthreads();

  const float b2v = b2[0];
  const float w2a = W2[4 * w + 0], w2b = W2[4 * w + 1];
  const float w2c = W2[4 * w + 2], w2d = W2[4 * w + 3];

  float pacc = 0.f;   // per-thread sum of unnormalized weights (stage 1)
  float uacc = 0.f;   // per-(dd,dg) partial of sum_l p_l * e_l[dd]

  // ================= stage 1: 4 chunks {64,64,64,8} =================
  for (int c = 0; c < 4; ++c) {
    const int base = c * CH;
    const int cnt = (base + CH <= LLEN) ? CH : (LLEN - base);
    const int nslot = cnt * 32;

    // -- stage rows: coalesced float4 gathers, up to 8 in flight --
    {
      float4 v[8];
#pragma unroll
      for (int it = 0; it < 8; ++it) {
        int s = tid + it * 256;
        if (s < nslot) {
          int gid = rows1[base + (s >> 5)];
          if (gid < 0) gid = 0;
          v[it] = it4[(size_t)gid * 32 + (s & 31)];
        }
      }
#pragma unroll
      for (int it = 0; it < 8; ++it) {
        int s = tid + it * 256;
        if (s < nslot) {
          float* dst = &ebuf[(s >> 5) * ESTR + 4 * (s & 31)];
          dst[0] = v[it].x; dst[1] = v[it].y; dst[2] = v[it].z; dst[3] = v[it].w;
        }
      }
    }
    __syncthreads();

    // -- matvec: wave w computes j in [4w,4w+4) for item=lane --
    if (lane < cnt) {
      float a0 = 0.f, a1 = 0.f, a2 = 0.f, a3 = 0.f;
      const float* er = &ebuf[lane * ESTR];
      const float* wc = &W1[(size_t)D * 16 + 4 * w];  // rows 128.., cols 4w..
#pragma unroll 16
      for (int d = 0; d < D; ++d) {
        float e = er[d];
        const float* wr = wc + d * 16;   // wave-uniform -> s_load_dwordx4
        a0 = fmaf(e, wr[0], a0);
        a1 = fmaf(e, wr[1], a1);
        a2 = fmaf(e, wr[2], a2);
        a3 = fmaf(e, wr[3], a3);
      }
      float hs = fmaxf(upart_sh[4 * w + 0] + a0, 0.f) * w2a;
      hs = fmaf(fmaxf(upart_sh[4 * w + 1] + a1, 0.f), w2b, hs);
      hs = fmaf(fmaxf(upart_sh[4 * w + 2] + a2, 0.f), w2c, hs);
      hs = fmaf(fmaxf(upart_sh[4 * w + 3] + a3, 0.f), w2d, hs);
      hspart[w * 65 + lane] = hs;
    }
    __syncthreads();

    // -- finalize logits -> unnormalized weights (no max-shift: |lg| << 80) --
    if (tid < cnt) {
      float lg = hspart[tid] + hspart[65 + tid] + hspart[130 + tid] +
                 hspart[195 + tid] + b2v;
      float p = (rows1[base + tid] >= 0) ? expf(lg) : 0.f;
      w_sh[tid] = p;
      pacc += p;
    }
    __syncthreads();

    // -- weighted accumulate (d-per-lane, conflict-free reads) --
    for (int l = dg; l < cnt; l += 2)
      uacc = fmaf(w_sh[l], ebuf[l * ESTR + dd], uacc);
    __syncthreads();  // ebuf/w_sh reused next chunk
  }

  // ---- u_long: reduce uacc, normalize, store to ebuf row 0 ----
  const float invS1 = 1.f / block_sum(pacc, red_sh);
  float* part2 = &ebuf[60 * ESTR];  // rows 60..63 dead after last chunk (cnt=8)
  part2[tid] = uacc;
  __syncthreads();
  if (tid < D) {
    float ul = (part2[tid] + part2[tid + D]) * invS1;
    ebuf[tid] = ul;  // ebuf row 0 = u_long (stage-2 item 0)
  }
  __syncthreads();

  // ================= stage 2: [u_long] + 50 S rows =================
  {
    const int nslot = SLEN * 32;  // rows -> ebuf rows 1..50
    float4 v[7];
#pragma unroll
    for (int it = 0; it < 7; ++it) {
      int s = tid + it * 256;
      if (s < nslot) {
        int gid = rowsS[s >> 5];
        if (gid < 0) gid = 0;
        v[it] = it4[(size_t)gid * 32 + (s & 31)];
      }
    }
#pragma unroll
    for (int it = 0; it < 7; ++it) {
      int s = tid + it * 256;
      if (s < nslot) {
        float* dst = &ebuf[((s >> 5) + 1) * ESTR + 4 * (s & 31)];
        dst[0] = v[it].x; dst[1] = v[it].y; dst[2] = v[it].z; dst[3] = v[it].w;
      }
    }
  }
  __syncthreads();

  const int n2 = 1 + SLEN;  // 51
  if (lane < n2) {
    float a0 = 0.f, a1 = 0.f, a2 = 0.f, a3 = 0.f;
    const float* er = &ebuf[lane * ESTR];
    const float* wc = &W1[(size_t)D * 16 + 4 * w];
#pragma unroll 16
    for (int d = 0; d < D; ++d) {
      float e = er[d];
      const float* wr = wc + d * 16;
      a0 = fmaf(e, wr[0], a0);
      a1 = fmaf(e, wr[1], a1);
      a2 = fmaf(e, wr[2], a2);
      a3 = fmaf(e, wr[3], a3);
    }
    float hs = fmaxf(upart_sh[4 * w + 0] + a0, 0.f) * w2a;
    hs = fmaf(fmaxf(upart_sh[4 * w + 1] + a1, 0.f), w2b, hs);
    hs = fmaf(fmaxf(upart_sh[4 * w + 2] + a2, 0.f), w2c, hs);
    hs = fmaf(fmaxf(upart_sh[4 * w + 3] + a3, 0.f), w2d, hs);
    hspart[w * 65 + lane] = hs;
  }
  __syncthreads();

  float p2 = 0.f;
  if (tid < n2) {
    float lg = hspart[tid] + hspart[65 + tid] + hspart[130 + tid] +
               hspart[195 + tid] + b2v;
    bool valid = (tid == 0) || (rowsS[tid - 1] >= 0);
    p2 = valid ? expf(lg) : 0.f;
    w_sh[tid] = p2;
  }
  const float invS2 = 1.f / block_sum(p2, red_sh);  // barrier publishes w_sh

  float uacc2 = 0.f;
  for (int l = dg; l < n2; l += 2)
    uacc2 = fmaf(w_sh[l], ebuf[l * ESTR + dd], uacc2);
  part2[tid] = uacc2;  // rows 60..63 untouched by stage 2 rows 0..50
  __syncthreads();

  // ---- score = dot(user_hybrid, item_emb) ----
  float sv = 0.f;
  if (tid < D) {
    float uh = (part2[tid] + part2[tid + D]) * invS2;
    sv = uh * item_table[(size_t)item_inputs[b] * D + tid];
  }
  float tot = block_sum(sv, red_sh);
  if (tid == 0) out[b] = tot;
}

extern "C" void kernel_launch(void* const* d_in, const int* in_sizes, int n_in,
                              void* d_out, int out_size, void* d_ws, size_t ws_size,
                              hipStream_t stream) {
  const float* user_table = (const float*)d_in[0];
  const float* item_table = (const float*)d_in[1];
  const float* W1 = (const float*)d_in[2];
  const float* b1 = (const float*)d_in[3];
  const float* W2 = (const float*)d_in[4];
  const float* b2 = (const float*)d_in[5];
  const int* user_inputs = (const int*)d_in[6];
  const int* L_inputs = (const int*)d_in[7];
  const int* S_inputs = (const int*)d_in[8];
  const int* item_inputs = (const int*)d_in[9];
  float* out = (float*)d_out;

  const int B = in_sizes[6];  // 4096
  din_kernel<<<B, 256, 0, stream>>>(user_table, item_table, W1, b1, W2, b2,
                                    user_inputs, L_inputs, S_inputs, item_inputs,
                                    out);
}